// Round 7
// baseline (96222.174 us; speedup 1.0000x reference)
//
#include <hip/hip_runtime.h>
#include <stdint.h>
#include <stddef.h>

typedef _Float16 f16;
typedef __attribute__((ext_vector_type(8))) _Float16 f16x8;
typedef __attribute__((ext_vector_type(4))) float f32x4;
typedef __attribute__((ext_vector_type(2))) double f64x2;

#define MFMA16(A,B,C) __builtin_amdgcn_mfma_f32_16x16x32_f16((A),(B),(C),0,0,0)

// B=128, T=1024, FEAT=256, HID=512, GATES=2048, K=768 (256 seq + 512 h)
// f64 VALU recurrence: per-step error ~1e-15 vs the np f64 reference; immune
// to this LSTM's ~1e4-1e5 step-error amplification (round-0/5/6 forensics:
// outputs 0/1 pass with this kernel). Output 2 depends only on the RNG
// bitstream convention, isolated to k4a.

// ---------------- workspace byte offsets ----------------
#define WS_CZB   0            // f64[128][512][4]  = 2 MiB
#define WS_C0    2097152      // f64[128*512]      = 512 KiB
#define WS_HBUF  2621440      // f64[2][128][512]  = 1 MiB (parity, batch, unit)
#define WS_HLAST 3670016      // f64[128*512]      = 512 KiB
#define WS_WOF   4194304      // f16[256*512]      = 256 KiB
#define WS_CTR   4456448      // u32 counters (8 groups x 16 stride)

// JAX threefry2x32 (20 rounds), host+device
__host__ __device__ __forceinline__ void tf2x32(uint32_t k0,uint32_t k1,uint32_t x0,uint32_t x1,
                                                uint32_t* o0,uint32_t* o1){
  uint32_t ks2 = k0 ^ k1 ^ 0x1BD11BDAu;
  uint32_t a = x0 + k0, b = x1 + k1;
  #define TF_R(rot) { a += b; b = (b<<(rot))|(b>>(32-(rot))); b ^= a; }
  TF_R(13) TF_R(15) TF_R(26) TF_R(6)  a += k1;  b += ks2 + 1u;
  TF_R(17) TF_R(29) TF_R(16) TF_R(24) a += ks2; b += k0  + 2u;
  TF_R(13) TF_R(15) TF_R(26) TF_R(6)  a += k0;  b += k1  + 3u;
  TF_R(17) TF_R(29) TF_R(16) TF_R(24) a += k1;  b += ks2 + 4u;
  TF_R(13) TF_R(15) TF_R(26) TF_R(6)  a += ks2; b += k0  + 5u;
  #undef TF_R
  *o0 = a; *o1 = b;
}

// ---------------- K1a: embed h0/c0 + Czb (z-part + biases), all f64 ----------------
__global__ void k1a(const float* __restrict__ z, const float* __restrict__ Wemb,
                    const float* __restrict__ bemb, const float* __restrict__ Wih,
                    const float* __restrict__ bih, const float* __restrict__ bhh,
                    double* __restrict__ h0, double* __restrict__ c0,
                    double* __restrict__ czb)
{
  int gi = blockIdx.x*256 + threadIdx.x;       // 128*3072 threads
  int b = gi / 3072, j = gi % 3072;
  const float* zr = z + b*256;
  if (j < 1024) {
    const float* wr = Wemb + j*256;
    double s = (double)bemb[j];
    for (int k=0;k<256;k++) s += (double)zr[k] * (double)wr[k];
    double v = tanh(s);
    if (j < 512) h0[b*512 + j] = v;            // hbuf parity 0, [b][u]
    else         c0[b*512 + (j-512)] = v;
  } else {
    int g = j - 1024;
    const float* wr = Wih + g*512 + 256;       // z-columns of W_ih
    double s = (double)bih[g] + (double)bhh[g];
    for (int k=0;k<256;k++) s += (double)zr[k] * (double)wr[k];
    int q = g >> 9, u = g & 511;
    czb[(b*512 + u)*4 + q] = s;
  }
}

// ---------------- K1b: W_out -> f16 for the bulk projection ----------------
__global__ void k1b(const float* __restrict__ Wout, f16* __restrict__ wof)
{
  int e0 = (blockIdx.x*256 + threadIdx.x)*4;   // 128 blocks
  #pragma unroll
  for (int j=0;j<4;j++) wof[e0+j] = (f16)Wout[e0+j];
}

// ---------------- K2: persistent f64 VALU LSTM ----------------
// 256 WGs x 512 thr (1/CU). WG = bG (16 batches) x nG (16 units).
// Thread = (qh = tid&1 gate pair, ul = (tid>>1)&15, bl = tid>>5).
// Owns gates q = 2qh, 2qh+1 of (b,u): two K=768 f64 dots. Gate exchange via
// one shfl_xor(1). h staged per-step into LDS [16][512] f64 (broadcast reads).
// Per-bG 32-WG monotonic counter barrier; seq part hoisted before the wait.
__global__ __launch_bounds__(512) void k2v(
    const float* __restrict__ seq, const float* __restrict__ Wih,
    const float* __restrict__ Whh,
    const double* __restrict__ czbv, const double* __restrict__ c0v,
    double* __restrict__ hbuf, f16* __restrict__ hs, double* __restrict__ hlast,
    unsigned int* __restrict__ ctr)
{
  __shared__ double hlds[16*512];              // 64 KiB
  const int tid = threadIdx.x;
  const int bid = blockIdx.x;
  const int bG = bid & 7, nG = bid >> 3;
  const int qh = tid & 1;
  const int ul = (tid >> 1) & 15;
  const int bl = tid >> 5;
  const int b  = bG*16 + bl;
  const int u  = nG*16 + ul;
  const int r0 = (qh*2)*512 + u;               // phys gate rows
  const int r1 = (qh*2+1)*512 + u;

  const float* wi0 = Wih + (size_t)r0*512;     // seq cols 0..255
  const float* wi1 = Wih + (size_t)r1*512;
  const float* wh0 = Whh + (size_t)r0*512;
  const float* wh1 = Whh + (size_t)r1*512;
  const float* xr_base = seq + (size_t)b*262144;

  const double cz0 = czbv[(b*512+u)*4 + qh*2];
  const double cz1 = czbv[(b*512+u)*4 + qh*2 + 1];
  double cc = c0v[b*512+u];

  unsigned int* mc = &ctr[bG*16];
  __syncthreads();

  for (int t = 0; t < 1024; ++t) {
    // -------- seq part (h-independent; overlaps barrier wait) --------
    double a00=0.,a01=0.,a02=0.,a03=0.;        // gate q0, 4 chains
    double a10=0.,a11=0.,a12=0.,a13=0.;        // gate q1
    const float* xr = xr_base + t*256;
    #pragma unroll 4
    for (int k = 0; k < 256; k += 4) {
      f32x4 xv = *(const f32x4*)&xr[k];
      f32x4 wa = *(const f32x4*)&wi0[k];
      f32x4 wb = *(const f32x4*)&wi1[k];
      double x0=(double)xv.x, x1=(double)xv.y, x2=(double)xv.z, x3=(double)xv.w;
      a00 += x0*(double)wa.x; a01 += x1*(double)wa.y;
      a02 += x2*(double)wa.z; a03 += x3*(double)wa.w;
      a10 += x0*(double)wb.x; a11 += x1*(double)wb.y;
      a12 += x2*(double)wb.z; a13 += x3*(double)wb.w;
    }

    // -------- wait: all 32 same-bG WGs published h_t --------
    if (t) {
      if (tid == 0) {
        unsigned tgt = 32u * (unsigned)t;
        while (__hip_atomic_load(mc, __ATOMIC_RELAXED, __HIP_MEMORY_SCOPE_AGENT) < tgt)
          __builtin_amdgcn_s_sleep(1);
        (void)__hip_atomic_load(mc, __ATOMIC_ACQUIRE, __HIP_MEMORY_SCOPE_AGENT);
      }
      __syncthreads();
    }

    // -------- stage h slice (16 batches x 512 units) into LDS --------
    const double* hrg = hbuf + (size_t)(t & 1)*65536;
    for (int i = tid; i < 4096; i += 512) {
      int bb = i >> 8;                         // 256 f64x2 per row
      int kk = (i & 255)*2;
      *(f64x2*)&hlds[bb*512 + kk] = *(const f64x2*)&hrg[(size_t)(bG*16+bb)*512 + kk];
    }
    __syncthreads();

    // -------- h part: K=512 --------
    const double* hr = hlds + bl*512;
    #pragma unroll 4
    for (int k = 0; k < 512; k += 4) {
      f64x2 hA = *(const f64x2*)&hr[k];
      f64x2 hB = *(const f64x2*)&hr[k+2];
      f32x4 wa = *(const f32x4*)&wh0[k];
      f32x4 wb = *(const f32x4*)&wh1[k];
      a00 += hA.x*(double)wa.x; a01 += hA.y*(double)wa.y;
      a02 += hB.x*(double)wa.z; a03 += hB.y*(double)wa.w;
      a10 += hA.x*(double)wb.x; a11 += hA.y*(double)wb.y;
      a12 += hB.x*(double)wb.z; a13 += hB.y*(double)wb.w;
    }

    double pa = ((a00+a01)+(a02+a03)) + cz0;   // pre-activation gate 2qh
    double pb = ((a10+a11)+(a12+a13)) + cz1;   // gate 2qh+1

    // -------- exchange with partner lane (other gate pair) --------
    double ox = __shfl_xor(pa, 1, 64);
    double oy = __shfl_xor(pb, 1, 64);
    double pi = qh ? ox : pa;
    double pf = qh ? oy : pb;
    double pg = qh ? pa : ox;
    double po = qh ? pb : oy;

    double ig = 1.0/(1.0 + exp(-pi));
    double fg = 1.0/(1.0 + exp(-pf));
    double gv = tanh(pg);
    double og = 1.0/(1.0 + exp(-po));
    double c2 = fg*cc + ig*gv;
    cc = c2;
    double hv = og*tanh(c2);

    double* hw = hbuf + (size_t)((t+1) & 1)*65536;
    hw[b*512 + u] = hv;                        // both qh threads write same value
    hs[(size_t)t*65536 + b*512 + u] = (f16)hv;
    if (t == 1023) hlast[b*512 + u] = hv;

    __syncthreads();
    if (tid == 0 && t < 1023) {
      __threadfence();
      __hip_atomic_fetch_add(mc, 1u, __ATOMIC_RELEASE, __HIP_MEMORY_SCOPE_AGENT);
    }
  }
}

// ---------------- K3: bulk output projection (f16 MFMA; 0.108 threshold) ----------------
__global__ __launch_bounds__(256) void k3(const f16* __restrict__ hsA, const f16* __restrict__ wof,
                                          const float* __restrict__ bout, float* __restrict__ out)
{
  int wg = blockIdx.x;                    // 2048 = 1024 Mtiles x 2 Nhalves
  int mt = wg >> 1, nh = wg & 1;
  int tid = threadIdx.x, wid = tid>>6, lane = tid&63;
  int l15 = lane&15, lk = lane>>4;
  int mrow = mt*128 + wid*32;
  f32x4 acc[2][8];
  #pragma unroll
  for (int mf=0;mf<2;mf++)
  #pragma unroll
  for (int nf=0;nf<8;nf++) acc[mf][nf] = (f32x4){0.f,0.f,0.f,0.f};
  int aoff0 = (mrow + l15)*512 + lk*8;
  int boff[8]; float bo[8];
  #pragma unroll
  for (int nf=0;nf<8;nf++){
    int o = nh*128 + nf*16 + l15;
    boff[nf] = o*512 + lk*8;
    bo[nf] = bout[o];
  }
  #pragma unroll 2
  for (int kb=0;kb<16;kb++){
    int k0 = kb*32;
    f16x8 a0 = *(const f16x8*)&hsA[(size_t)aoff0 + k0];
    f16x8 a1 = *(const f16x8*)&hsA[(size_t)aoff0 + 16*512 + k0];
    f16x8 bf[8];
    #pragma unroll
    for (int nf=0;nf<8;nf++) bf[nf] = *(const f16x8*)&wof[boff[nf]+k0];
    #pragma unroll
    for (int nf=0;nf<8;nf++){
      acc[0][nf] = MFMA16(a0, bf[nf], acc[0][nf]);
      acc[1][nf] = MFMA16(a1, bf[nf], acc[1][nf]);
    }
  }
  #pragma unroll
  for (int mf=0;mf<2;mf++)
  #pragma unroll
  for (int nf=0;nf<8;nf++)
  #pragma unroll
  for (int r=0;r<4;r++){
    int m = mrow + mf*16 + lk*4 + r;
    int b = m & 127, tt = m >> 7;
    int o = nh*128 + nf*16 + l15;
    out[((size_t)b*1024 + tt)*256 + o] = acc[mf][nf][r] + bo[nf];
  }
}

// ---------------- K3b: t=1023 logits from f64 h (f64 dot) ----------------
__global__ void k3b(const double* __restrict__ hlast, const float* __restrict__ Wout,
                    const float* __restrict__ bout, float* __restrict__ out)
{
  int b = blockIdx.x, o = threadIdx.x;
  const double* hr = hlast + b*512;
  const float* wr = Wout + o*512;
  double s = (double)bout[o];
  for (int k=0;k<512;k++) s += hr[k] * (double)wr[k];
  out[((size_t)b*1024 + 1023)*256 + o] = (float)s;
}

// ---------------- K4a: categorical (threefry-partitionable, XOR-fold) ----------------
// partitionable (JAX >= 0.4.30 default): per-element u64 counter n; block
// (x0 = n>>32 = 0, x1 = n); 32-bit draw = bits1 ^ bits2 (XOR of the two
// output words — _threefry_random_bits_partitionable's 32-bit path).
// [y1-truncation falsified by round 6's clean f64 experiment.]
__global__ void k4a(const float* __restrict__ outr, float* __restrict__ dout,
                    uint32_t fk0, uint32_t fk1)
{
  int b = blockIdx.x, o = threadIdx.x;
  float logit = outr[((size_t)b*1024 + 1023)*256 + o];
  uint32_t n = (uint32_t)(b*256 + o);
  uint32_t y0, y1;
  tf2x32(fk0, fk1, 0u, n, &y0, &y1);
  uint32_t bits = y0 ^ y1;
  float fl = __uint_as_float((bits>>9) | 0x3f800000u) - 1.0f;
  const float TINY = 1.17549435e-38f;
  float u = fmaxf(fl + TINY, TINY);
  float gum = -logf(-logf(u));
  float score = logit + gum;
  __shared__ float sv[256]; __shared__ int si[256];
  sv[o] = score; si[o] = o; __syncthreads();
  for (int s=128;s>0;s>>=1){
    if (o < s){
      float v2 = sv[o+s]; int i2 = si[o+s];
      if (v2 > sv[o] || (v2 == sv[o] && i2 < si[o])) { sv[o] = v2; si[o] = i2; }
    }
    __syncthreads();
  }
  int widx = si[0];
  dout[(size_t)33554433 + (size_t)b*262144 + 1023*256 + o] = (o == widx) ? 1.0f : 0.0f;
  if (b==0 && o==0) dout[33554432] = 0.0f;
}

// ---------------- K4b: sampled_output[:, :1023] = seq_input[:, 1:] ----------------
__global__ void k4b(const float* __restrict__ seq, float* __restrict__ dout)
{
  int gi = blockIdx.x*256 + threadIdx.x;
  int b = gi / 65472;
  int rr = (gi % 65472)*4;
  f32x4 v = *(const f32x4*)&seq[(size_t)b*262144 + 256 + rr];
  size_t d = (size_t)33554433 + (size_t)b*262144 + rr;
  dout[d]   = v.x; dout[d+1] = v.y; dout[d+2] = v.z; dout[d+3] = v.w;
}

extern "C" void kernel_launch(void* const* d_in, const int* in_sizes, int n_in,
                              void* d_out, int out_size, void* d_ws, size_t ws_size,
                              hipStream_t stream) {
  const float* z    = (const float*)d_in[0];
  const float* seq  = (const float*)d_in[1];
  const float* Wemb = (const float*)d_in[2];
  const float* bemb = (const float*)d_in[3];
  const float* Wih  = (const float*)d_in[4];
  const float* Whh  = (const float*)d_in[5];
  const float* bih  = (const float*)d_in[6];
  const float* bhh  = (const float*)d_in[7];
  const float* Wout = (const float*)d_in[8];
  const float* bout = (const float*)d_in[9];
  float* out = (float*)d_out;
  char* ws = (char*)d_ws;

  double* czb   = (double*)(ws + WS_CZB);
  double* c0    = (double*)(ws + WS_C0);
  double* hbuf  = (double*)(ws + WS_HBUF);
  double* hlast = (double*)(ws + WS_HLAST);
  f16*    wof   = (f16*)(ws + WS_WOF);
  unsigned int* ctr = (unsigned int*)(ws + WS_CTR);

  // hs (f16, 128 MiB) aliased into the sampled_output half of d_out;
  // consumed by k3 before k4a/k4b overwrite it.
  f16* hs = (f16*)(out + 33554432);

  uint32_t fk0, fk1;
  tf2x32(0u, 0u, 0u, 1234u, &fk0, &fk1);   // fold_in(key(0), 1234)

  hipMemsetAsync(ws + WS_CTR, 0, 512, stream);
  k1a<<<1536, 256, 0, stream>>>(z, Wemb, bemb, Wih, bih, bhh, hbuf, c0, czb);
  k1b<<<128, 256, 0, stream>>>(Wout, wof);
  k2v<<<256, 512, 0, stream>>>(seq, Wih, Whh, czb, c0, hbuf, hs, hlast, ctr);
  k3<<<2048, 256, 0, stream>>>(hs, wof, bout, out);
  k3b<<<128, 256, 0, stream>>>(hlast, Wout, bout, out);
  k4a<<<128, 256, 0, stream>>>(out, out, fk0, fk1);
  k4b<<<32736, 256, 0, stream>>>(seq, out);
}

// Round 9
// 43211.887 us; speedup vs baseline: 2.2268x; 2.2268x over previous
//
#include <hip/hip_runtime.h>
#include <stdint.h>
#include <stddef.h>

typedef _Float16 f16;
typedef __attribute__((ext_vector_type(8))) _Float16 f16x8;
typedef __attribute__((ext_vector_type(4))) float f32x4;
typedef __attribute__((ext_vector_type(2))) double f64x2;

#define MFMA16(A,B,C) __builtin_amdgcn_mfma_f32_16x16x32_f16((A),(B),(C),0,0,0)

// B=128, T=1024, FEAT=256, HID=512, GATES=2048, K=768 (256 seq + 512 h)
// f64 recurrence (ref=np is f64-grade; step-error gain ~1e5). Round-7 passed
// at 96ms (stall-bound); round-8 pinned weights in VGPRs but had an
// address-carry bug in the x-stage swizzle (odd threads, chunks with bit2 set:
// bit-6 added twice -> carry into bit 7 -> write escaped its swizzle chunk).
// This round: identical structure, swizzle applied as a pure XOR on the
// 3-bit within-chunk pair index.

// ---------------- workspace byte offsets ----------------
#define WS_CZB   0            // f64[128][512][4]  = 2 MiB
#define WS_C0    2097152      // f64[128*512]      = 512 KiB
#define WS_HBUF  2621440      // f64[2][128][512]  = 1 MiB (parity, batch, unit)
#define WS_HLAST 3670016      // f64[128*512]      = 512 KiB
#define WS_WOF   4194304      // f16[256*512]      = 256 KiB
#define WS_CTR   4456448      // u32 counters (8 groups x 16 stride)

// JAX threefry2x32 (20 rounds), host+device
__host__ __device__ __forceinline__ void tf2x32(uint32_t k0,uint32_t k1,uint32_t x0,uint32_t x1,
                                                uint32_t* o0,uint32_t* o1){
  uint32_t ks2 = k0 ^ k1 ^ 0x1BD11BDAu;
  uint32_t a = x0 + k0, b = x1 + k1;
  #define TF_R(rot) { a += b; b = (b<<(rot))|(b>>(32-(rot))); b ^= a; }
  TF_R(13) TF_R(15) TF_R(26) TF_R(6)  a += k1;  b += ks2 + 1u;
  TF_R(17) TF_R(29) TF_R(16) TF_R(24) a += ks2; b += k0  + 2u;
  TF_R(13) TF_R(15) TF_R(26) TF_R(6)  a += k0;  b += k1  + 3u;
  TF_R(17) TF_R(29) TF_R(16) TF_R(24) a += k1;  b += ks2 + 4u;
  TF_R(13) TF_R(15) TF_R(26) TF_R(6)  a += ks2; b += k0  + 5u;
  #undef TF_R
  *o0 = a; *o1 = b;
}

// ---------------- K1a: embed h0/c0 + Czb (z-part + biases), all f64 ----------------
__global__ void k1a(const float* __restrict__ z, const float* __restrict__ Wemb,
                    const float* __restrict__ bemb, const float* __restrict__ Wih,
                    const float* __restrict__ bih, const float* __restrict__ bhh,
                    double* __restrict__ h0, double* __restrict__ c0,
                    double* __restrict__ czb)
{
  int gi = blockIdx.x*256 + threadIdx.x;       // 128*3072 threads
  int b = gi / 3072, j = gi % 3072;
  const float* zr = z + b*256;
  if (j < 1024) {
    const float* wr = Wemb + j*256;
    double s = (double)bemb[j];
    for (int k=0;k<256;k++) s += (double)zr[k] * (double)wr[k];
    double v = tanh(s);
    if (j < 512) h0[b*512 + j] = v;            // hbuf parity 0, [b][u]
    else         c0[b*512 + (j-512)] = v;
  } else {
    int g = j - 1024;
    const float* wr = Wih + g*512 + 256;       // z-columns of W_ih
    double s = (double)bih[g] + (double)bhh[g];
    for (int k=0;k<256;k++) s += (double)zr[k] * (double)wr[k];
    int q = g >> 9, u = g & 511;
    czb[(b*512 + u)*4 + q] = s;
  }
}

// ---------------- K1b: W_out -> f16 for the bulk projection ----------------
__global__ void k1b(const float* __restrict__ Wout, f16* __restrict__ wof)
{
  int e0 = (blockIdx.x*256 + threadIdx.x)*4;   // 128 blocks
  #pragma unroll
  for (int j=0;j<4;j++) wof[e0+j] = (f16)Wout[e0+j];
}

// ---------------- K2: persistent f64 LSTM, weights-in-registers ----------------
// 256 WGs x 512 thr (1/CU). WG = bG (16 batches) x nG (16 units = 64 gate rows).
// lane = kc*4 + rs (kc = K-chunk 0..15, rs = gate q 0..3); wave w owns units
// {2w, 2w+1}. Each lane holds 2 rows' K-chunks in f64 VGPRs:
//   seq: Wih[r][kc*16..+16] (16 f64), h: Whh[r][kc*32..+32] (32 f64) -> 96 f64.
// x_t staged f32->f64 into LDS; h_t staged from global; both XOR-swizzled on
// the 3-bit within-128B-chunk pair index (x: swz = chunk&7; h: swz = (chunk>>1)&7)
// so lane-kc chunk reads are conflict-free. Partials reduced by shfl_xor
// butterfly (offsets 4..32); activations phase-split; per-bG 32-WG monotonic
// barrier with the seq part hoisted before the wait.
__global__ __launch_bounds__(512, 2) void k2r(
    const float* __restrict__ seq, const float* __restrict__ Wih,
    const float* __restrict__ Whh,
    const double* __restrict__ czbv, const double* __restrict__ c0v,
    double* __restrict__ hbuf, f16* __restrict__ hs, double* __restrict__ hlast,
    unsigned int* __restrict__ ctr)
{
  __shared__ double xl[4096];      // 32KB  x_t  [bb][256]
  __shared__ double hl[8192];      // 64KB  h_t  [bb][512]
  __shared__ double sc[1024];      // 8KB   raw gate sums [bb][q][ul]
  __shared__ double czl[1024];     // 8KB   biases, same layout

  const int tid = threadIdx.x;
  const int bid = blockIdx.x;
  const int bG = bid & 7, nG = bid >> 3;
  const int w = tid >> 6, lane = tid & 63;
  const int kc = lane >> 2, rs = lane & 3;
  const int XR = (kc & 7) << 4;                        // read-side swizzle const

  // physical gate rows for this lane's two units
  const int uA = nG*16 + 2*w;
  const size_t rA = (size_t)(rs*512 + uA);
  const size_t rB = rA + 1;

  // ---- one-time: weights -> f64 registers (never reloaded) ----
  double wsA[16], wsB[16], whA[32], whB[32];
  {
    const float* pA = Wih + rA*512 + kc*16;
    const float* pB = Wih + rB*512 + kc*16;
    #pragma unroll
    for (int j=0;j<16;j++){ wsA[j] = (double)pA[j]; wsB[j] = (double)pB[j]; }
    const float* qA = Whh + rA*512 + kc*32;
    const float* qB = Whh + rB*512 + kc*32;
    #pragma unroll
    for (int j=0;j<32;j++){ whA[j] = (double)qA[j]; whB[j] = (double)qB[j]; }
  }

  // ---- one-time: biases into LDS (czl[bb*64 + q*16 + ul]) ----
  for (int s = tid; s < 1024; s += 512) {
    int bb = s >> 6, q = (s >> 4) & 3, ul = s & 15;
    czl[s] = czbv[(size_t)((bG*16+bb)*512 + nG*16 + ul)*4 + q];
  }

  // elementwise ownership (tid < 256): cc in register for all 1024 steps
  double cc = 0.0;
  if (tid < 256) cc = c0v[(size_t)(bG*16 + (tid>>4))*512 + nG*16 + (tid&15)];

  // staging geometry
  const int lane5 = tid & 31;
  const int srow  = tid >> 5;        // 0..15 (batch row for staging)
  const int xchk  = lane5 >> 1;      // x: 128B chunk 0..15 (2 threads/chunk)
  const int xhalf = lane5 & 1;       // which 4-pair half
  const int xswz  = xchk & 7;
  const int hswz  = (lane5 >> 1) & 7;  // h: chunk = lane5, swz = (chunk>>1)&7

  unsigned int* mc = &ctr[bG*16];
  __syncthreads();

  for (int t = 0; t < 1024; ++t) {
    // -------- stage x_t: f32 -> f64, XOR-swizzled (8 elems/thread) --------
    {
      const float* xsrc = seq + (size_t)(bG*16 + srow)*262144 + (size_t)t*256 + lane5*8;
      f32x4 v0 = *(const f32x4*)xsrc;
      f32x4 v1 = *(const f32x4*)(xsrc + 4);
      char* wbase = (char*)xl + srow*2048 + xchk*128;
      f64x2 pr0 = {(double)v0.x, (double)v0.y};
      f64x2 pr1 = {(double)v0.z, (double)v0.w};
      f64x2 pr2 = {(double)v1.x, (double)v1.y};
      f64x2 pr3 = {(double)v1.z, (double)v1.w};
      *(f64x2*)(wbase + (((xhalf*4 + 0) ^ xswz) << 4)) = pr0;
      *(f64x2*)(wbase + (((xhalf*4 + 1) ^ xswz) << 4)) = pr1;
      *(f64x2*)(wbase + (((xhalf*4 + 2) ^ xswz) << 4)) = pr2;
      *(f64x2*)(wbase + (((xhalf*4 + 3) ^ xswz) << 4)) = pr3;
    }
    __syncthreads();

    // -------- seq partials (h-independent; overlaps the barrier wait) --------
    for (int bb = 0; bb < 16; ++bb) {
      const char* xb = (const char*)xl + bb*2048 + kc*128;
      double aA0=0., aA1=0., aB0=0., aB1=0.;
      #pragma unroll
      for (int j2 = 0; j2 < 8; ++j2) {
        f64x2 xv = *(const f64x2*)(xb + ((j2*16) ^ XR));
        aA0 += wsA[2*j2]   * xv.x;
        aA1 += wsA[2*j2+1] * xv.y;
        aB0 += wsB[2*j2]   * xv.x;
        aB1 += wsB[2*j2+1] * xv.y;
      }
      double aA = aA0 + aA1, aB = aB0 + aB1;
      #pragma unroll
      for (int off = 4; off < 64; off <<= 1) {
        aA += __shfl_xor(aA, off, 64);
        aB += __shfl_xor(aB, off, 64);
      }
      if (kc == 0) sc[bb*64 + rs*16 + 2*w]     = aA;
      if (kc == 1) sc[bb*64 + rs*16 + 2*w + 1] = aB;
    }

    // -------- wait: all 32 same-bG WGs published h_t --------
    if (t) {
      if (tid == 0) {
        unsigned tgt = 32u * (unsigned)t;
        while (__hip_atomic_load(mc, __ATOMIC_RELAXED, __HIP_MEMORY_SCOPE_AGENT) < tgt)
          __builtin_amdgcn_s_sleep(1);
        (void)__hip_atomic_load(mc, __ATOMIC_ACQUIRE, __HIP_MEMORY_SCOPE_AGENT);
      }
      __syncthreads();
    }

    // -------- stage h_t: global f64 -> LDS, XOR-swizzled (16 elems/thread) --------
    {
      const double* hsrc = hbuf + (size_t)(t & 1)*65536 + (size_t)(bG*16 + srow)*512 + lane5*16;
      char* wbase = (char*)hl + srow*4096 + lane5*128;
      #pragma unroll
      for (int g = 0; g < 8; ++g) {
        f64x2 hv = *(const f64x2*)(hsrc + 2*g);
        *(f64x2*)(wbase + ((g ^ hswz) << 4)) = hv;
      }
    }
    __syncthreads();

    // -------- h partials (K=512) --------
    for (int bb = 0; bb < 16; ++bb) {
      const char* hb2 = (const char*)hl + bb*4096 + kc*256;
      double aA0=0., aA1=0., aB0=0., aB1=0.;
      #pragma unroll
      for (int j2 = 0; j2 < 16; ++j2) {
        f64x2 hv = *(const f64x2*)(hb2 + ((j2*16) ^ XR));
        aA0 += whA[2*j2]   * hv.x;
        aA1 += whA[2*j2+1] * hv.y;
        aB0 += whB[2*j2]   * hv.x;
        aB1 += whB[2*j2+1] * hv.y;
      }
      double aA = aA0 + aA1, aB = aB0 + aB1;
      #pragma unroll
      for (int off = 4; off < 64; off <<= 1) {
        aA += __shfl_xor(aA, off, 64);
        aB += __shfl_xor(aB, off, 64);
      }
      if (kc == 0) sc[bb*64 + rs*16 + 2*w]     += aA;
      if (kc == 1) sc[bb*64 + rs*16 + 2*w + 1] += aB;
    }
    __syncthreads();

    // -------- phase 1: bias + activation, 2 slots/thread (1024 total) --------
    {
      int s0 = tid*2;
      #pragma unroll
      for (int e = 0; e < 2; ++e) {
        int s = s0 + e;
        int q = (s >> 4) & 3;
        double v = sc[s] + czl[s];
        v = (q == 2) ? tanh(v) : 1.0/(1.0 + exp(-v));
        sc[s] = v;
      }
    }
    __syncthreads();

    // -------- phase 2: cell update (tid < 256; cc in register) --------
    if (tid < 256) {
      int bb = tid >> 4, ul = tid & 15;
      double ig = sc[bb*64 +      ul];
      double fg = sc[bb*64 + 16 + ul];
      double gv = sc[bb*64 + 32 + ul];
      double og = sc[bb*64 + 48 + ul];
      double c2 = fg*cc + ig*gv;
      cc = c2;
      double hv = og*tanh(c2);
      size_t gidx = (size_t)(bG*16 + bb)*512 + nG*16 + ul;
      hbuf[(size_t)((t+1)&1)*65536 + gidx] = hv;
      hs[(size_t)t*65536 + gidx] = (f16)hv;
      if (t == 1023) hlast[gidx] = hv;
    }
    __syncthreads();

    if (tid == 0 && t < 1023) {
      __threadfence();
      __hip_atomic_fetch_add(mc, 1u, __ATOMIC_RELEASE, __HIP_MEMORY_SCOPE_AGENT);
    }
  }
}

// ---------------- K3: bulk output projection (f16 MFMA; 0.108 threshold) ----------------
__global__ __launch_bounds__(256) void k3(const f16* __restrict__ hsA, const f16* __restrict__ wof,
                                          const float* __restrict__ bout, float* __restrict__ out)
{
  int wg = blockIdx.x;                    // 2048 = 1024 Mtiles x 2 Nhalves
  int mt = wg >> 1, nh = wg & 1;
  int tid = threadIdx.x, wid = tid>>6, lane = tid&63;
  int l15 = lane&15, lk = lane>>4;
  int mrow = mt*128 + wid*32;
  f32x4 acc[2][8];
  #pragma unroll
  for (int mf=0;mf<2;mf++)
  #pragma unroll
  for (int nf=0;nf<8;nf++) acc[mf][nf] = (f32x4){0.f,0.f,0.f,0.f};
  int aoff0 = (mrow + l15)*512 + lk*8;
  int boff[8]; float bo[8];
  #pragma unroll
  for (int nf=0;nf<8;nf++){
    int o = nh*128 + nf*16 + l15;
    boff[nf] = o*512 + lk*8;
    bo[nf] = bout[o];
  }
  #pragma unroll 2
  for (int kb=0;kb<16;kb++){
    int k0 = kb*32;
    f16x8 a0 = *(const f16x8*)&hsA[(size_t)aoff0 + k0];
    f16x8 a1 = *(const f16x8*)&hsA[(size_t)aoff0 + 16*512 + k0];
    f16x8 bf[8];
    #pragma unroll
    for (int nf=0;nf<8;nf++) bf[nf] = *(const f16x8*)&wof[boff[nf]+k0];
    #pragma unroll
    for (int nf=0;nf<8;nf++){
      acc[0][nf] = MFMA16(a0, bf[nf], acc[0][nf]);
      acc[1][nf] = MFMA16(a1, bf[nf], acc[1][nf]);
    }
  }
  #pragma unroll
  for (int mf=0;mf<2;mf++)
  #pragma unroll
  for (int nf=0;nf<8;nf++)
  #pragma unroll
  for (int r=0;r<4;r++){
    int m = mrow + mf*16 + lk*4 + r;
    int b = m & 127, tt = m >> 7;
    int o = nh*128 + nf*16 + l15;
    out[((size_t)b*1024 + tt)*256 + o] = acc[mf][nf][r] + bo[nf];
  }
}

// ---------------- K3b: t=1023 logits from f64 h (f64 dot) ----------------
__global__ void k3b(const double* __restrict__ hlast, const float* __restrict__ Wout,
                    const float* __restrict__ bout, float* __restrict__ out)
{
  int b = blockIdx.x, o = threadIdx.x;
  const double* hr = hlast + b*512;
  const float* wr = Wout + o*512;
  double s = (double)bout[o];
  for (int k=0;k<512;k++) s += hr[k] * (double)wr[k];
  out[((size_t)b*1024 + 1023)*256 + o] = (float)s;
}

// ---------------- K4a: categorical (threefry-partitionable, XOR-fold) ----------------
// VERIFIED round 7: per-element u64 counter n; block (x0=0, x1=n);
// 32-bit draw = y0 ^ y1.
__global__ void k4a(const float* __restrict__ outr, float* __restrict__ dout,
                    uint32_t fk0, uint32_t fk1)
{
  int b = blockIdx.x, o = threadIdx.x;
  float logit = outr[((size_t)b*1024 + 1023)*256 + o];
  uint32_t n = (uint32_t)(b*256 + o);
  uint32_t y0, y1;
  tf2x32(fk0, fk1, 0u, n, &y0, &y1);
  uint32_t bits = y0 ^ y1;
  float fl = __uint_as_float((bits>>9) | 0x3f800000u) - 1.0f;
  const float TINY = 1.17549435e-38f;
  float u = fmaxf(fl + TINY, TINY);
  float gum = -logf(-logf(u));
  float score = logit + gum;
  __shared__ float sv[256]; __shared__ int si[256];
  sv[o] = score; si[o] = o; __syncthreads();
  for (int s=128;s>0;s>>=1){
    if (o < s){
      float v2 = sv[o+s]; int i2 = si[o+s];
      if (v2 > sv[o] || (v2 == sv[o] && i2 < si[o])) { sv[o] = v2; si[o] = i2; }
    }
    __syncthreads();
  }
  int widx = si[0];
  dout[(size_t)33554433 + (size_t)b*262144 + 1023*256 + o] = (o == widx) ? 1.0f : 0.0f;
  if (b==0 && o==0) dout[33554432] = 0.0f;
}

// ---------------- K4b: sampled_output[:, :1023] = seq_input[:, 1:] ----------------
__global__ void k4b(const float* __restrict__ seq, float* __restrict__ dout)
{
  int gi = blockIdx.x*256 + threadIdx.x;
  int b = gi / 65472;
  int rr = (gi % 65472)*4;
  f32x4 v = *(const f32x4*)&seq[(size_t)b*262144 + 256 + rr];
  size_t d = (size_t)33554433 + (size_t)b*262144 + rr;
  dout[d]   = v.x; dout[d+1] = v.y; dout[d+2] = v.z; dout[d+3] = v.w;
}

extern "C" void kernel_launch(void* const* d_in, const int* in_sizes, int n_in,
                              void* d_out, int out_size, void* d_ws, size_t ws_size,
                              hipStream_t stream) {
  const float* z    = (const float*)d_in[0];
  const float* seq  = (const float*)d_in[1];
  const float* Wemb = (const float*)d_in[2];
  const float* bemb = (const float*)d_in[3];
  const float* Wih  = (const float*)d_in[4];
  const float* Whh  = (const float*)d_in[5];
  const float* bih  = (const float*)d_in[6];
  const float* bhh  = (const float*)d_in[7];
  const float* Wout = (const float*)d_in[8];
  const float* bout = (const float*)d_in[9];
  float* out = (float*)d_out;
  char* ws = (char*)d_ws;

  double* czb   = (double*)(ws + WS_CZB);
  double* c0    = (double*)(ws + WS_C0);
  double* hbuf  = (double*)(ws + WS_HBUF);
  double* hlast = (double*)(ws + WS_HLAST);
  f16*    wof   = (f16*)(ws + WS_WOF);
  unsigned int* ctr = (unsigned int*)(ws + WS_CTR);

  // hs (f16, 128 MiB) aliased into the sampled_output half of d_out;
  // consumed by k3 before k4a/k4b overwrite it.
  f16* hs = (f16*)(out + 33554432);

  uint32_t fk0, fk1;
  tf2x32(0u, 0u, 0u, 1234u, &fk0, &fk1);   // fold_in(key(0), 1234)

  hipMemsetAsync(ws + WS_CTR, 0, 512, stream);
  k1a<<<1536, 256, 0, stream>>>(z, Wemb, bemb, Wih, bih, bhh, hbuf, c0, czb);
  k1b<<<128, 256, 0, stream>>>(Wout, wof);
  k2r<<<256, 512, 0, stream>>>(seq, Wih, Whh, czb, c0, hbuf, hs, hlast, ctr);
  k3<<<2048, 256, 0, stream>>>(hs, wof, bout, out);
  k3b<<<128, 256, 0, stream>>>(hlast, Wout, bout, out);
  k4a<<<128, 256, 0, stream>>>(out, out, fk0, fk1);
  k4b<<<32736, 256, 0, stream>>>(seq, out);
}

// Round 10
// 38875.732 us; speedup vs baseline: 2.4751x; 1.1115x over previous
//
#include <hip/hip_runtime.h>
#include <stdint.h>
#include <stddef.h>

typedef _Float16 f16;
typedef __attribute__((ext_vector_type(8))) _Float16 f16x8;
typedef __attribute__((ext_vector_type(4))) float f32x4;
typedef __attribute__((ext_vector_type(2))) double f64x2;

#define MFMA16(A,B,C) __builtin_amdgcn_mfma_f32_16x16x32_f16((A),(B),(C),0,0,0)

// B=128, T=1024, FEAT=256, HID=512, GATES=2048, K=768 (256 seq + 512 h)
// f64 recurrence (ref=np is f64-grade; step-error gain ~1e5).
// Round-9 (passed, 39.6ms k2): VGPR=128 proves weights were NOT register-
// resident (96 f64 needs 192 VGPR) -> compiler remat'd loads+cvt in-loop;
// DS pipe ~900 instr/wave/step (384 reads + 2x butterfly 512) was critical.
// This round: (1) asm-pin weights in VGPRs, (2) fuse seq+h per bb -> single
// butterfly (saves 256 b32 DS-ops/wave/step), wait moved before bb loop.

// ---------------- workspace byte offsets ----------------
#define WS_CZB   0            // f64[128][512][4]  = 2 MiB
#define WS_C0    2097152      // f64[128*512]      = 512 KiB
#define WS_HBUF  2621440      // f64[2][128][512]  = 1 MiB (parity, batch, unit)
#define WS_HLAST 3670016      // f64[128*512]      = 512 KiB
#define WS_WOF   4194304      // f16[256*512]      = 256 KiB
#define WS_CTR   4456448      // u32 counters (8 groups x 16 stride)

// JAX threefry2x32 (20 rounds), host+device
__host__ __device__ __forceinline__ void tf2x32(uint32_t k0,uint32_t k1,uint32_t x0,uint32_t x1,
                                                uint32_t* o0,uint32_t* o1){
  uint32_t ks2 = k0 ^ k1 ^ 0x1BD11BDAu;
  uint32_t a = x0 + k0, b = x1 + k1;
  #define TF_R(rot) { a += b; b = (b<<(rot))|(b>>(32-(rot))); b ^= a; }
  TF_R(13) TF_R(15) TF_R(26) TF_R(6)  a += k1;  b += ks2 + 1u;
  TF_R(17) TF_R(29) TF_R(16) TF_R(24) a += ks2; b += k0  + 2u;
  TF_R(13) TF_R(15) TF_R(26) TF_R(6)  a += k0;  b += k1  + 3u;
  TF_R(17) TF_R(29) TF_R(16) TF_R(24) a += k1;  b += ks2 + 4u;
  TF_R(13) TF_R(15) TF_R(26) TF_R(6)  a += ks2; b += k0  + 5u;
  #undef TF_R
  *o0 = a; *o1 = b;
}

// ---------------- K1a: embed h0/c0 + Czb (z-part + biases), all f64 ----------------
__global__ void k1a(const float* __restrict__ z, const float* __restrict__ Wemb,
                    const float* __restrict__ bemb, const float* __restrict__ Wih,
                    const float* __restrict__ bih, const float* __restrict__ bhh,
                    double* __restrict__ h0, double* __restrict__ c0,
                    double* __restrict__ czb)
{
  int gi = blockIdx.x*256 + threadIdx.x;       // 128*3072 threads
  int b = gi / 3072, j = gi % 3072;
  const float* zr = z + b*256;
  if (j < 1024) {
    const float* wr = Wemb + j*256;
    double s = (double)bemb[j];
    for (int k=0;k<256;k++) s += (double)zr[k] * (double)wr[k];
    double v = tanh(s);
    if (j < 512) h0[b*512 + j] = v;            // hbuf parity 0, [b][u]
    else         c0[b*512 + (j-512)] = v;
  } else {
    int g = j - 1024;
    const float* wr = Wih + g*512 + 256;       // z-columns of W_ih
    double s = (double)bih[g] + (double)bhh[g];
    for (int k=0;k<256;k++) s += (double)zr[k] * (double)wr[k];
    int q = g >> 9, u = g & 511;
    czb[(b*512 + u)*4 + q] = s;
  }
}

// ---------------- K1b: W_out -> f16 for the bulk projection ----------------
__global__ void k1b(const float* __restrict__ Wout, f16* __restrict__ wof)
{
  int e0 = (blockIdx.x*256 + threadIdx.x)*4;   // 128 blocks
  #pragma unroll
  for (int j=0;j<4;j++) wof[e0+j] = (f16)Wout[e0+j];
}

// ---------------- K2: persistent f64 LSTM, weights pinned in VGPRs ----------------
// 256 WGs x 512 thr (1/CU). WG = bG (16 batches) x nG (16 units = 64 gate rows).
// lane = kc*4 + rs; wave w owns units {2w, 2w+1}. Lane holds 2 rows' K-chunks
// as f64 in VGPRs (96 f64 = 192 VGPR), asm-pinned against remat. Per bb:
// fused seq(32 FMA)+h(64 FMA) into 2 chains/row, ONE 4-round shfl butterfly.
// x/h staged to XOR-swizzled LDS; per-bG 32-WG monotonic counter barrier.
__global__ __launch_bounds__(512, 2) void k2s(
    const float* __restrict__ seq, const float* __restrict__ Wih,
    const float* __restrict__ Whh,
    const double* __restrict__ czbv, const double* __restrict__ c0v,
    double* __restrict__ hbuf, f16* __restrict__ hs, double* __restrict__ hlast,
    unsigned int* __restrict__ ctr)
{
  __shared__ double xl[4096];      // 32KB  x_t  [bb][256]
  __shared__ double hl[8192];      // 64KB  h_t  [bb][512]
  __shared__ double sc[1024];      // 8KB   gate sums [bb][q][ul]
  __shared__ double czl[1024];     // 8KB   biases, same layout

  const int tid = threadIdx.x;
  const int bid = blockIdx.x;
  const int bG = bid & 7, nG = bid >> 3;
  const int w = tid >> 6, lane = tid & 63;
  const int kc = lane >> 2, rs = lane & 3;
  const int XR = (kc & 7) << 4;                        // read-side swizzle const

  // physical gate rows for this lane's two units
  const int uA = nG*16 + 2*w;
  const size_t rA = (size_t)(rs*512 + uA);
  const size_t rB = rA + 1;

  // ---- one-time: weights -> f64 registers, asm-pinned (never reloaded) ----
  double wsA[16], wsB[16], whA[32], whB[32];
  {
    const float* pA = Wih + rA*512 + kc*16;
    const float* pB = Wih + rB*512 + kc*16;
    #pragma unroll
    for (int j=0;j<16;j++){ wsA[j] = (double)pA[j]; wsB[j] = (double)pB[j]; }
    const float* qA = Whh + rA*512 + kc*32;
    const float* qB = Whh + rB*512 + kc*32;
    #pragma unroll
    for (int j=0;j<32;j++){ whA[j] = (double)qA[j]; whB[j] = (double)qB[j]; }
    // pin: asm redefines each value so the compiler cannot rematerialize
    // the global load (rule-17 trick); forces true VGPR residency.
    #pragma unroll
    for (int j=0;j<16;j++){ asm volatile("" : "+v"(wsA[j])); asm volatile("" : "+v"(wsB[j])); }
    #pragma unroll
    for (int j=0;j<32;j++){ asm volatile("" : "+v"(whA[j])); asm volatile("" : "+v"(whB[j])); }
  }

  // ---- one-time: biases into LDS (czl[bb*64 + q*16 + ul]) ----
  for (int s = tid; s < 1024; s += 512) {
    int bb = s >> 6, q = (s >> 4) & 3, ul = s & 15;
    czl[s] = czbv[(size_t)((bG*16+bb)*512 + nG*16 + ul)*4 + q];
  }

  // elementwise ownership (tid < 256): cc in register for all 1024 steps
  double cc = 0.0;
  if (tid < 256) cc = c0v[(size_t)(bG*16 + (tid>>4))*512 + nG*16 + (tid&15)];

  // staging geometry
  const int lane5 = tid & 31;
  const int srow  = tid >> 5;        // 0..15 (batch row for staging)
  const int xchk  = lane5 >> 1;      // x: 128B chunk 0..15 (2 threads/chunk)
  const int xhalf = lane5 & 1;       // which 4-pair half
  const int xswz  = xchk & 7;
  const int hswz  = (lane5 >> 1) & 7;  // h: chunk = lane5, swz = (chunk>>1)&7

  unsigned int* mc = &ctr[bG*16];
  __syncthreads();

  for (int t = 0; t < 1024; ++t) {
    // -------- stage x_t: f32 -> f64, XOR-swizzled (8 elems/thread) --------
    {
      const float* xsrc = seq + (size_t)(bG*16 + srow)*262144 + (size_t)t*256 + lane5*8;
      f32x4 v0 = *(const f32x4*)xsrc;
      f32x4 v1 = *(const f32x4*)(xsrc + 4);
      char* wbase = (char*)xl + srow*2048 + xchk*128;
      f64x2 pr0 = {(double)v0.x, (double)v0.y};
      f64x2 pr1 = {(double)v0.z, (double)v0.w};
      f64x2 pr2 = {(double)v1.x, (double)v1.y};
      f64x2 pr3 = {(double)v1.z, (double)v1.w};
      *(f64x2*)(wbase + (((xhalf*4 + 0) ^ xswz) << 4)) = pr0;
      *(f64x2*)(wbase + (((xhalf*4 + 1) ^ xswz) << 4)) = pr1;
      *(f64x2*)(wbase + (((xhalf*4 + 2) ^ xswz) << 4)) = pr2;
      *(f64x2*)(wbase + (((xhalf*4 + 3) ^ xswz) << 4)) = pr3;
    }

    // -------- wait: all 32 same-bG WGs published h_t --------
    if (t) {
      if (tid == 0) {
        unsigned tgt = 32u * (unsigned)t;
        while (__hip_atomic_load(mc, __ATOMIC_RELAXED, __HIP_MEMORY_SCOPE_AGENT) < tgt)
          __builtin_amdgcn_s_sleep(1);
        (void)__hip_atomic_load(mc, __ATOMIC_ACQUIRE, __HIP_MEMORY_SCOPE_AGENT);
      }
    }
    __syncthreads();

    // -------- stage h_t: global f64 -> LDS, XOR-swizzled (16 elems/thread) --------
    {
      const double* hsrc = hbuf + (size_t)(t & 1)*65536 + (size_t)(bG*16 + srow)*512 + lane5*16;
      char* wbase = (char*)hl + srow*4096 + lane5*128;
      #pragma unroll
      for (int g = 0; g < 8; ++g) {
        f64x2 hv = *(const f64x2*)(hsrc + 2*g);
        *(f64x2*)(wbase + ((g ^ hswz) << 4)) = hv;
      }
    }
    __syncthreads();

    // -------- fused seq+h partials per bb; ONE butterfly per bb --------
    for (int bb = 0; bb < 16; ++bb) {
      const char* xb  = (const char*)xl + bb*2048 + kc*128;
      const char* hb2 = (const char*)hl + bb*4096 + kc*256;
      double aA0=0., aA1=0., aB0=0., aB1=0.;
      #pragma unroll
      for (int j2 = 0; j2 < 8; ++j2) {
        f64x2 xv = *(const f64x2*)(xb + ((j2*16) ^ XR));
        aA0 += wsA[2*j2]   * xv.x;
        aA1 += wsA[2*j2+1] * xv.y;
        aB0 += wsB[2*j2]   * xv.x;
        aB1 += wsB[2*j2+1] * xv.y;
      }
      #pragma unroll
      for (int j2 = 0; j2 < 16; ++j2) {
        f64x2 hv = *(const f64x2*)(hb2 + ((j2*16) ^ XR));
        aA0 += whA[2*j2]   * hv.x;
        aA1 += whA[2*j2+1] * hv.y;
        aB0 += whB[2*j2]   * hv.x;
        aB1 += whB[2*j2+1] * hv.y;
      }
      double aA = aA0 + aA1, aB = aB0 + aB1;
      #pragma unroll
      for (int off = 4; off < 64; off <<= 1) {
        aA += __shfl_xor(aA, off, 64);
        aB += __shfl_xor(aB, off, 64);
      }
      if (kc == 0) sc[bb*64 + rs*16 + 2*w]     = aA;
      if (kc == 1) sc[bb*64 + rs*16 + 2*w + 1] = aB;
    }
    __syncthreads();

    // -------- phase 1: bias + activation, 2 slots/thread (1024 total) --------
    {
      int s0 = tid*2;
      #pragma unroll
      for (int e = 0; e < 2; ++e) {
        int s = s0 + e;
        int q = (s >> 4) & 3;
        double v = sc[s] + czl[s];
        v = (q == 2) ? tanh(v) : 1.0/(1.0 + exp(-v));
        sc[s] = v;
      }
    }
    __syncthreads();

    // -------- phase 2: cell update (tid < 256; cc in register) --------
    if (tid < 256) {
      int bb = tid >> 4, ul = tid & 15;
      double ig = sc[bb*64 +      ul];
      double fg = sc[bb*64 + 16 + ul];
      double gv = sc[bb*64 + 32 + ul];
      double og = sc[bb*64 + 48 + ul];
      double c2 = fg*cc + ig*gv;
      cc = c2;
      double hv = og*tanh(c2);
      size_t gidx = (size_t)(bG*16 + bb)*512 + nG*16 + ul;
      hbuf[(size_t)((t+1)&1)*65536 + gidx] = hv;
      hs[(size_t)t*65536 + gidx] = (f16)hv;
      if (t == 1023) hlast[gidx] = hv;
    }
    __syncthreads();

    if (tid == 0 && t < 1023) {
      __threadfence();
      __hip_atomic_fetch_add(mc, 1u, __ATOMIC_RELEASE, __HIP_MEMORY_SCOPE_AGENT);
    }
  }
}

// ---------------- K3: bulk output projection (f16 MFMA; 0.108 threshold) ----------------
__global__ __launch_bounds__(256) void k3(const f16* __restrict__ hsA, const f16* __restrict__ wof,
                                          const float* __restrict__ bout, float* __restrict__ out)
{
  int wg = blockIdx.x;                    // 2048 = 1024 Mtiles x 2 Nhalves
  int mt = wg >> 1, nh = wg & 1;
  int tid = threadIdx.x, wid = tid>>6, lane = tid&63;
  int l15 = lane&15, lk = lane>>4;
  int mrow = mt*128 + wid*32;
  f32x4 acc[2][8];
  #pragma unroll
  for (int mf=0;mf<2;mf++)
  #pragma unroll
  for (int nf=0;nf<8;nf++) acc[mf][nf] = (f32x4){0.f,0.f,0.f,0.f};
  int aoff0 = (mrow + l15)*512 + lk*8;
  int boff[8]; float bo[8];
  #pragma unroll
  for (int nf=0;nf<8;nf++){
    int o = nh*128 + nf*16 + l15;
    boff[nf] = o*512 + lk*8;
    bo[nf] = bout[o];
  }
  #pragma unroll 2
  for (int kb=0;kb<16;kb++){
    int k0 = kb*32;
    f16x8 a0 = *(const f16x8*)&hsA[(size_t)aoff0 + k0];
    f16x8 a1 = *(const f16x8*)&hsA[(size_t)aoff0 + 16*512 + k0];
    f16x8 bf[8];
    #pragma unroll
    for (int nf=0;nf<8;nf++) bf[nf] = *(const f16x8*)&wof[boff[nf]+k0];
    #pragma unroll
    for (int nf=0;nf<8;nf++){
      acc[0][nf] = MFMA16(a0, bf[nf], acc[0][nf]);
      acc[1][nf] = MFMA16(a1, bf[nf], acc[1][nf]);
    }
  }
  #pragma unroll
  for (int mf=0;mf<2;mf++)
  #pragma unroll
  for (int nf=0;nf<8;nf++)
  #pragma unroll
  for (int r=0;r<4;r++){
    int m = mrow + mf*16 + lk*4 + r;
    int b = m & 127, tt = m >> 7;
    int o = nh*128 + nf*16 + l15;
    out[((size_t)b*1024 + tt)*256 + o] = acc[mf][nf][r] + bo[nf];
  }
}

// ---------------- K3b: t=1023 logits from f64 h (f64 dot) ----------------
__global__ void k3b(const double* __restrict__ hlast, const float* __restrict__ Wout,
                    const float* __restrict__ bout, float* __restrict__ out)
{
  int b = blockIdx.x, o = threadIdx.x;
  const double* hr = hlast + b*512;
  const float* wr = Wout + o*512;
  double s = (double)bout[o];
  for (int k=0;k<512;k++) s += hr[k] * (double)wr[k];
  out[((size_t)b*1024 + 1023)*256 + o] = (float)s;
}

// ---------------- K4a: categorical (threefry-partitionable, XOR-fold) ----------------
// VERIFIED round 7: per-element u64 counter n; block (x0=0, x1=n);
// 32-bit draw = y0 ^ y1.
__global__ void k4a(const float* __restrict__ outr, float* __restrict__ dout,
                    uint32_t fk0, uint32_t fk1)
{
  int b = blockIdx.x, o = threadIdx.x;
  float logit = outr[((size_t)b*1024 + 1023)*256 + o];
  uint32_t n = (uint32_t)(b*256 + o);
  uint32_t y0, y1;
  tf2x32(fk0, fk1, 0u, n, &y0, &y1);
  uint32_t bits = y0 ^ y1;
  float fl = __uint_as_float((bits>>9) | 0x3f800000u) - 1.0f;
  const float TINY = 1.17549435e-38f;
  float u = fmaxf(fl + TINY, TINY);
  float gum = -logf(-logf(u));
  float score = logit + gum;
  __shared__ float sv[256]; __shared__ int si[256];
  sv[o] = score; si[o] = o; __syncthreads();
  for (int s=128;s>0;s>>=1){
    if (o < s){
      float v2 = sv[o+s]; int i2 = si[o+s];
      if (v2 > sv[o] || (v2 == sv[o] && i2 < si[o])) { sv[o] = v2; si[o] = i2; }
    }
    __syncthreads();
  }
  int widx = si[0];
  dout[(size_t)33554433 + (size_t)b*262144 + 1023*256 + o] = (o == widx) ? 1.0f : 0.0f;
  if (b==0 && o==0) dout[33554432] = 0.0f;
}

// ---------------- K4b: sampled_output[:, :1023] = seq_input[:, 1:] ----------------
__global__ void k4b(const float* __restrict__ seq, float* __restrict__ dout)
{
  int gi = blockIdx.x*256 + threadIdx.x;
  int b = gi / 65472;
  int rr = (gi % 65472)*4;
  f32x4 v = *(const f32x4*)&seq[(size_t)b*262144 + 256 + rr];
  size_t d = (size_t)33554433 + (size_t)b*262144 + rr;
  dout[d]   = v.x; dout[d+1] = v.y; dout[d+2] = v.z; dout[d+3] = v.w;
}

extern "C" void kernel_launch(void* const* d_in, const int* in_sizes, int n_in,
                              void* d_out, int out_size, void* d_ws, size_t ws_size,
                              hipStream_t stream) {
  const float* z    = (const float*)d_in[0];
  const float* seq  = (const float*)d_in[1];
  const float* Wemb = (const float*)d_in[2];
  const float* bemb = (const float*)d_in[3];
  const float* Wih  = (const float*)d_in[4];
  const float* Whh  = (const float*)d_in[5];
  const float* bih  = (const float*)d_in[6];
  const float* bhh  = (const float*)d_in[7];
  const float* Wout = (const float*)d_in[8];
  const float* bout = (const float*)d_in[9];
  float* out = (float*)d_out;
  char* ws = (char*)d_ws;

  double* czb   = (double*)(ws + WS_CZB);
  double* c0    = (double*)(ws + WS_C0);
  double* hbuf  = (double*)(ws + WS_HBUF);
  double* hlast = (double*)(ws + WS_HLAST);
  f16*    wof   = (f16*)(ws + WS_WOF);
  unsigned int* ctr = (unsigned int*)(ws + WS_CTR);

  // hs (f16, 128 MiB) aliased into the sampled_output half of d_out;
  // consumed by k3 before k4a/k4b overwrite it.
  f16* hs = (f16*)(out + 33554432);

  uint32_t fk0, fk1;
  tf2x32(0u, 0u, 0u, 1234u, &fk0, &fk1);   // fold_in(key(0), 1234)

  hipMemsetAsync(ws + WS_CTR, 0, 512, stream);
  k1a<<<1536, 256, 0, stream>>>(z, Wemb, bemb, Wih, bih, bhh, hbuf, c0, czb);
  k1b<<<128, 256, 0, stream>>>(Wout, wof);
  k2s<<<256, 512, 0, stream>>>(seq, Wih, Whh, czb, c0, hbuf, hs, hlast, ctr);
  k3<<<2048, 256, 0, stream>>>(hs, wof, bout, out);
  k3b<<<128, 256, 0, stream>>>(hlast, Wout, bout, out);
  k4a<<<128, 256, 0, stream>>>(out, out, fk0, fk1);
  k4b<<<32736, 256, 0, stream>>>(seq, out);
}